// Round 4
// baseline (426.036 us; speedup 1.0000x reference)
//
#include <hip/hip_runtime.h>

typedef __bf16 bf16_t;
typedef __attribute__((ext_vector_type(8))) __bf16 bh8;
typedef __attribute__((ext_vector_type(4))) __bf16 bh4;
typedef __attribute__((ext_vector_type(4))) float f32x4;

#define DEV static __device__ __forceinline__

typedef __attribute__((address_space(3))) void lds_void;
typedef const __attribute__((address_space(1))) void glb_void;

// async global->LDS, 16B per lane; LDS dest = wave-uniform base + lane*16
DEV void async16(const bf16_t* g, bf16_t* l) {
  __builtin_amdgcn_global_load_lds((glb_void*)g, (lds_void*)l, 16, 0, 0);
}

// ---------- helpers ----------
DEV float wave_sum(float v) {
#pragma unroll
  for (int m = 32; m > 0; m >>= 1) v += __shfl_xor(v, m, 64);
  return v;
}

// assumes blockDim.x == 256 (4 waves)
DEV float block_sum(float v, float* sbuf) {
  v = wave_sum(v);
  int wid = threadIdx.x >> 6;
  if ((threadIdx.x & 63) == 0) sbuf[wid] = v;
  __syncthreads();
  float r = sbuf[0] + sbuf[1] + sbuf[2] + sbuf[3];
  __syncthreads();
  return r;
}

// ---------- fused weight-row norms: all 5 weights in one dispatch ----------
// s layout: [0:1024) cond, [1024:2048) qkv, [2048:3072) out, [3072:4096) mlp1, [4096:8192) mlp2
__global__ void k_wnorm_all(const float* __restrict__ w_cond, const float* __restrict__ w_qkv,
                            const float* __restrict__ w_out, const float* __restrict__ w_mlp1,
                            const float* __restrict__ w_mlp2, float* __restrict__ s) {
  __shared__ float sbuf[4];
  int id = blockIdx.x;
  const float* W; int N, K, row;
  if (id < 1024)      { W = w_cond; N = 2048; K = 1024; row = id; }
  else if (id < 2048) { W = w_qkv;  N = 3072; K = 1024; row = id - 1024; }
  else if (id < 3072) { W = w_out;  N = 1024; K = 1024; row = id - 2048; }
  else if (id < 4096) { W = w_mlp1; N = 4096; K = 1024; row = id - 3072; }
  else                { W = w_mlp2; N = 1024; K = 4096; row = id - 4096; }
  const float4* wr = (const float4*)(W + (size_t)row * N);
  float acc = 0.f;
  for (int i = threadIdx.x; i < (N >> 2); i += 256) {
    float4 w = wr[i];
    acc += w.x*w.x + w.y*w.y + w.z*w.z + w.w*w.w;
  }
  float tot = block_sum(acc, sbuf);
  if (threadIdx.x == 0) {
    float norm = sqrtf(tot);
    s[id] = 1.0f / ((norm * sqrtf((float)N) + 1e-4f) * sqrtf((float)K));
  }
}

// ---------- fused transpose+scale+cast: Wt[n][k] = bf16(W[k][n]*s[k]) ----------
__global__ void k_wtrans_all(const float* __restrict__ w_cond, const float* __restrict__ w_qkv,
                             const float* __restrict__ w_out, const float* __restrict__ w_mlp1,
                             const float* __restrict__ w_mlp2, const float* __restrict__ sall,
                             bf16_t* __restrict__ wt_cond, bf16_t* __restrict__ wt_qkv,
                             bf16_t* __restrict__ wt_out, bf16_t* __restrict__ wt_mlp1,
                             bf16_t* __restrict__ wt_mlp2) {
  __shared__ float tile[64][65];
  int id = blockIdx.x;
  const float* W; const float* s; bf16_t* Wt; int K, N, n0, k0;
  if (id < 512)       { W=w_cond; s=sall;      Wt=wt_cond; K=1024; N=2048; int l=id;      n0=(l&31)*64; k0=(l>>5)*64; }
  else if (id < 1280) { W=w_qkv;  s=sall+1024; Wt=wt_qkv;  K=1024; N=3072; int l=id-512;  n0=(l%48)*64; k0=(l/48)*64; }
  else if (id < 1536) { W=w_out;  s=sall+2048; Wt=wt_out;  K=1024; N=1024; int l=id-1280; n0=(l&15)*64; k0=(l>>4)*64; }
  else if (id < 2560) { W=w_mlp1; s=sall+3072; Wt=wt_mlp1; K=1024; N=4096; int l=id-1536; n0=(l&63)*64; k0=(l>>6)*64; }
  else                { W=w_mlp2; s=sall+4096; Wt=wt_mlp2; K=4096; N=1024; int l=id-2560; n0=(l&15)*64; k0=(l>>4)*64; }
  int tx = threadIdx.x & 63, ty = threadIdx.x >> 6;
  for (int r = ty; r < 64; r += 4)
    tile[r][tx] = W[(size_t)(k0 + r) * N + n0 + tx] * s[k0 + r];
  __syncthreads();
  for (int r = ty; r < 64; r += 4)
    Wt[(size_t)(n0 + r) * K + k0 + tx] = (bf16_t)tile[tx][r];
}

// ---------- conditioning: gs[b][j] = (silu(c[b])/0.596) . wn_cond[:,j] ----------
__global__ void k_cond(const float* __restrict__ c, const bf16_t* __restrict__ wt,
                       float* __restrict__ gs) {
  __shared__ float cc[4][1024];
  int t = threadIdx.x;
  for (int i = t; i < 4096; i += 256) {
    int b = i >> 10, col = i & 1023;
    float x = c[b * 1024 + col];
    float sig = 1.f / (1.f + __expf(-x));
    cc[b][col] = x * sig * (1.f / 0.596f);
  }
  __syncthreads();
  int wid = t >> 6, lane = t & 63;
  int j = blockIdx.x * 4 + wid;
  const bf16_t* wr = wt + (size_t)j * 1024;
  float acc0 = 0, acc1 = 0, acc2 = 0, acc3 = 0;
  for (int i = lane; i < 1024; i += 64) {
    float w = (float)wr[i];
    acc0 += cc[0][i] * w; acc1 += cc[1][i] * w;
    acc2 += cc[2][i] * w; acc3 += cc[3][i] * w;
  }
  float v0 = wave_sum(acc0), v1 = wave_sum(acc1), v2 = wave_sum(acc2), v3 = wave_sum(acc3);
  if (lane == 0) {
    gs[0 * 2048 + j] = v0; gs[1 * 2048 + j] = v1;
    gs[2 * 2048 + j] = v2; gs[3 * 2048 + j] = v3;
  }
}

// ---------- xc = bf16(pixel_norm(x)*(1+gain)+shift), one block per row ----------
__global__ void k_xcond(const float* __restrict__ x, const float* __restrict__ gs,
                        bf16_t* __restrict__ xc) {
  __shared__ float sbuf[4];
  int row = blockIdx.x, b = row >> 10, t = threadIdx.x;
  float4 v = ((const float4*)(x + (size_t)row * 1024))[t];
  float ss = v.x*v.x + v.y*v.y + v.z*v.z + v.w*v.w;
  float tot = block_sum(ss, sbuf);
  float r = rsqrtf(tot * (1.f/1024.f) + 1e-4f);
  float4 g  = ((const float4*)(gs + b * 2048))[t];
  float4 sh = ((const float4*)(gs + b * 2048 + 1024))[t];
  bh4 o;
  o[0] = (bf16_t)(v.x * r * (1.f + g.x) + sh.x);
  o[1] = (bf16_t)(v.y * r * (1.f + g.y) + sh.y);
  o[2] = (bf16_t)(v.z * r * (1.f + g.z) + sh.z);
  o[3] = (bf16_t)(v.w * r * (1.f + g.w) + sh.w);
  *(bh4*)(xc + (size_t)row * 1024 + t * 4) = o;
}

// ---------- bf16 MFMA GEMM (m97 structure + clustered XCD swizzle) ----------
// grid.z = split-K index; C offset by z*M*N; klen = K per split.
// Swizzle: flat%8 -> XCD (round-robin dispatch). Each XCD owns npx=gx/8
// contiguous n-blocks. Within an XCD, blocks walk m-supergroups of 8
// (n fastest inside a group) so the co-resident window's working set is
// <= 8 A-tiles (2 MB) + npx B-tiles (<=1 MB) < 4 MB L2 -> no thrash;
// the B-strip stays resident across all m.
__global__ __launch_bounds__(256) void k_gemm(const bf16_t* __restrict__ A,
                                              const bf16_t* __restrict__ Bt,
                                              bf16_t* __restrict__ C,
                                              int M, int N, int K, int klen) {
  __shared__ bf16_t As[128][32];
  __shared__ bf16_t Bs[128][32];
  const unsigned gx = gridDim.x;
  const unsigned flat = blockIdx.x + gx * blockIdx.y;
  const unsigned npx = gx >> 3;
  const unsigned xcd = flat & 7, o = flat >> 3;
  const unsigned grp = npx * 8;
  const unsigned mg = o / grp, r = o % grp;
  const int m0 = (mg * 8 + r / npx) * 128;
  const int n0 = (xcd * npx + r % npx) * 128;
  const size_t kbeg = (size_t)blockIdx.z * klen;
  C += (size_t)blockIdx.z * M * N;
  const int t = threadIdx.x, lane = t & 63, wid = t >> 6;
  const int l15 = lane & 15, quad = lane >> 4;
  const int wm = (wid >> 1) * 64, wn = (wid & 1) * 64;
  const int r0 = t >> 2, kc0 = (t & 3) * 8;
  const bf16_t* Ag0 = A + (size_t)(m0 + r0) * K + kbeg + kc0;
  const bf16_t* Ag1 = Ag0 + (size_t)64 * K;
  const bf16_t* Bg0 = Bt + (size_t)(n0 + r0) * K + kbeg + kc0;
  const bf16_t* Bg1 = Bg0 + (size_t)64 * K;
  bf16_t* lA0 = &As[0][0] + wid * 512;   // wave-uniform LDS dest
  bf16_t* lB0 = &Bs[0][0] + wid * 512;
  f32x4 acc[4][4] = {};
  for (int k0 = 0; k0 < klen; k0 += 32) {
    async16(Ag0 + k0, lA0);
    async16(Ag1 + k0, lA0 + 2048);
    async16(Bg0 + k0, lB0);
    async16(Bg1 + k0, lB0 + 2048);
    __syncthreads();
    bh8 a[4], bb[4];
#pragma unroll
    for (int i = 0; i < 4; i++) a[i]  = *(const bh8*)&As[wm + i*16 + l15][quad*8];
#pragma unroll
    for (int j = 0; j < 4; j++) bb[j] = *(const bh8*)&Bs[wn + j*16 + l15][quad*8];
#pragma unroll
    for (int i = 0; i < 4; i++)
#pragma unroll
      for (int j = 0; j < 4; j++)
        acc[i][j] = __builtin_amdgcn_mfma_f32_16x16x32_bf16(a[i], bb[j], acc[i][j], 0, 0, 0);
    __syncthreads();
  }
#pragma unroll
  for (int i = 0; i < 4; i++)
#pragma unroll
    for (int j = 0; j < 4; j++)
#pragma unroll
      for (int r2 = 0; r2 < 4; r2++)
        C[(size_t)(m0 + wm + i*16 + quad*4 + r2) * N + n0 + wn + j*16 + l15] =
            (bf16_t)acc[i][j][r2];
}

// ---------- qkv (bf16 in): pixel_norm per 1024-chunk + per-head L2 norm; write [B,NH,N,DH] ----------
__global__ void k_qkvnorm(const bf16_t* __restrict__ qkv, bf16_t* __restrict__ qo,
                          bf16_t* __restrict__ ko, bf16_t* __restrict__ vo) {
  __shared__ float sbuf[4];
  const int row = blockIdx.x, b = row >> 10, n = row & 1023, t = threadIdx.x;
  const bf16_t* rp = qkv + (size_t)row * 3072;
  bh4 q4 = *(const bh4*)(rp + t * 4);
  bh4 k4 = *(const bh4*)(rp + 1024 + t * 4);
  bh4 v4 = *(const bh4*)(rp + 2048 + t * 4);
  float4 q = {(float)q4[0], (float)q4[1], (float)q4[2], (float)q4[3]};
  float4 k = {(float)k4[0], (float)k4[1], (float)k4[2], (float)k4[3]};
  float4 v = {(float)v4[0], (float)v4[1], (float)v4[2], (float)v4[3]};
  float sq = q.x*q.x + q.y*q.y + q.z*q.z + q.w*q.w;
  float sk = k.x*k.x + k.y*k.y + k.z*k.z + k.w*k.w;
  float sv = v.x*v.x + v.y*v.y + v.z*v.z + v.w*v.w;
  float tq = block_sum(sq, sbuf);
  float tk = block_sum(sk, sbuf);
  float tv = block_sum(sv, sbuf);
  float rq = rsqrtf(tq * (1.f/1024.f) + 1e-4f);
  float rk = rsqrtf(tk * (1.f/1024.f) + 1e-4f);
  float rv = rsqrtf(tv * (1.f/1024.f) + 1e-4f);
  float hq = sq, hk = sk;   // per-head sums: 16 consecutive threads = one head (within a wave)
#pragma unroll
  for (int m = 1; m < 16; m <<= 1) { hq += __shfl_xor(hq, m, 64); hk += __shfl_xor(hk, m, 64); }
  float qs = rq * rsqrtf(rq*rq*hq + 1e-6f);
  float ks = rk * rsqrtf(rk*rk*hk + 1e-6f);
  int h = t >> 4, d = (t & 15) * 4;
  size_t base = ((size_t)(b * 16 + h) * 1024 + n) * 64 + d;
  bh4 oq, okk, ov;
  oq[0]=(bf16_t)(q.x*qs); oq[1]=(bf16_t)(q.y*qs); oq[2]=(bf16_t)(q.z*qs); oq[3]=(bf16_t)(q.w*qs);
  okk[0]=(bf16_t)(k.x*ks); okk[1]=(bf16_t)(k.y*ks); okk[2]=(bf16_t)(k.z*ks); okk[3]=(bf16_t)(k.w*ks);
  ov[0]=(bf16_t)(v.x*rv); ov[1]=(bf16_t)(v.y*rv); ov[2]=(bf16_t)(v.z*rv); ov[3]=(bf16_t)(v.w*rv);
  *(bh4*)(qo + base) = oq;
  *(bh4*)(ko + base) = okk;
  *(bh4*)(vo + base) = ov;
}

// ---------- attention: scores bounded in [-1/8,1/8] -> no max-subtraction needed ----------
__global__ __launch_bounds__(256) void k_attn(const bf16_t* __restrict__ Q,
                                              const bf16_t* __restrict__ K,
                                              const bf16_t* __restrict__ V,
                                              bf16_t* __restrict__ O) {
  __shared__ bf16_t Qs[128][72];
  __shared__ bf16_t Ks[64][72];
  __shared__ bf16_t Vt[64][72];   // Vt[dh][kv]
  __shared__ bf16_t Ps[128][72];
  const int qt = blockIdx.x, bh = blockIdx.y;
  const int b = bh >> 4, h = bh & 15;
  const int t = threadIdx.x, lane = t & 63, wid = t >> 6;
  const int l15 = lane & 15, quad = lane >> 4;
  const int strip = wid * 32;
  const bf16_t* Qg = Q + ((size_t)bh * 1024 + qt * 128) * 64;
  const bf16_t* Kg = K + (size_t)bh * 1024 * 64;
  const bf16_t* Vg = V + (size_t)bh * 1024 * 64;
  for (int i = t; i < 1024; i += 256) {
    int r = i >> 3, p = (i & 7) * 8;
    *(bh8*)&Qs[r][p] = *(const bh8*)(Qg + r * 64 + p);
  }
  f32x4 o[2][4] = {};
  float rs[2][4] = {};
  __syncthreads();
  for (int kv0 = 0; kv0 < 1024; kv0 += 64) {
    for (int i = t; i < 512; i += 256) {
      int r = i >> 3, p = (i & 7) * 8;
      *(bh8*)&Ks[r][p] = *(const bh8*)(Kg + (size_t)(kv0 + r) * 64 + p);
      bh8 vv = *(const bh8*)(Vg + (size_t)(kv0 + r) * 64 + p);
#pragma unroll
      for (int j = 0; j < 8; j++) Vt[p + j][r] = vv[j];
    }
    __syncthreads();
    // S = Q Kt for this wave's 32-row strip
    f32x4 s[2][4] = {};
#pragma unroll
    for (int kc = 0; kc < 2; kc++) {
      bh8 aq[2], bk[4];
#pragma unroll
      for (int i = 0; i < 2; i++) aq[i] = *(const bh8*)&Qs[strip + i*16 + l15][kc*32 + quad*8];
#pragma unroll
      for (int j = 0; j < 4; j++) bk[j] = *(const bh8*)&Ks[j*16 + l15][kc*32 + quad*8];
#pragma unroll
      for (int i = 0; i < 2; i++)
#pragma unroll
        for (int j = 0; j < 4; j++)
          s[i][j] = __builtin_amdgcn_mfma_f32_16x16x32_bf16(aq[i], bk[j], s[i][j], 0, 0, 0);
    }
    // P = exp(S/8); accumulate per-lane rowsums; C-layout -> LDS -> A-layout
#pragma unroll
    for (int i = 0; i < 2; i++)
#pragma unroll
      for (int j = 0; j < 4; j++)
#pragma unroll
        for (int r = 0; r < 4; r++) {
          float p = __expf(s[i][j][r] * 0.125f);
          bf16_t pb = (bf16_t)p;
          rs[i][r] += (float)pb;   // keep rs consistent with bf16 P fed to PV
          Ps[strip + i*16 + quad*4 + r][j*16 + l15] = pb;
        }
    // O += P @ V  (wave reads only its own Ps strip -> no extra barrier needed)
#pragma unroll
    for (int kc = 0; kc < 2; kc++) {
      bh8 ap[2], bv[4];
#pragma unroll
      for (int i = 0; i < 2; i++) ap[i] = *(const bh8*)&Ps[strip + i*16 + l15][kc*32 + quad*8];
#pragma unroll
      for (int j = 0; j < 4; j++) bv[j] = *(const bh8*)&Vt[j*16 + l15][kc*32 + quad*8];
#pragma unroll
      for (int i = 0; i < 2; i++)
#pragma unroll
        for (int j = 0; j < 4; j++)
          o[i][j] = __builtin_amdgcn_mfma_f32_16x16x32_bf16(ap[i], bv[j], o[i][j], 0, 0, 0);
    }
    __syncthreads();
  }
  // finalize rowsums: sum across the 16 column-lanes of each quad; O rows match rs rows
#pragma unroll
  for (int i = 0; i < 2; i++)
#pragma unroll
    for (int r = 0; r < 4; r++) {
      float v = rs[i][r];
      v += __shfl_xor(v, 1, 64); v += __shfl_xor(v, 2, 64);
      v += __shfl_xor(v, 4, 64); v += __shfl_xor(v, 8, 64);
      float inv = 1.f / v;
      int n = qt * 128 + strip + i*16 + quad*4 + r;
#pragma unroll
      for (int j = 0; j < 4; j++)
        O[((size_t)b * 1024 + n) * 1024 + h*64 + j*16 + l15] = (bf16_t)(o[i][j][r] * inv);
    }
}

// ---------- x1 = mp_add(x, pixel_norm(y0+y1)*exp(ag)) [bf16 out]; xc2 = bf16(pixel_norm(x1)*(1+g)+s) ----------
__global__ void k_amerge(const bf16_t* __restrict__ y, const float* __restrict__ x,
                         const float* __restrict__ gs, const float* __restrict__ again,
                         bf16_t* __restrict__ x1, bf16_t* __restrict__ xc2) {
  __shared__ float sbuf[4];
  int row = blockIdx.x, b = row >> 10, t = threadIdx.x;
  const size_t PS = (size_t)4096 * 1024;   // split-K partial stride (elements)
  bh4 a0 = *(const bh4*)(y + (size_t)row * 1024 + t * 4);
  bh4 a1 = *(const bh4*)(y + PS + (size_t)row * 1024 + t * 4);
  float4 yv;
  yv.x = (float)a0[0] + (float)a1[0]; yv.y = (float)a0[1] + (float)a1[1];
  yv.z = (float)a0[2] + (float)a1[2]; yv.w = (float)a0[3] + (float)a1[3];
  float4 xv = ((const float4*)(x + (size_t)row * 1024))[t];
  float ss = yv.x*yv.x + yv.y*yv.y + yv.z*yv.z + yv.w*yv.w;
  float tot = block_sum(ss, sbuf);
  float r = rsqrtf(tot * (1.f/1024.f) + 1e-4f);
  float ag = __expf(again[0]);
  const float C1 = 0.7f / 0.76157731059f, C2 = 0.3f / 0.76157731059f; // /sqrt(0.58)
  float4 xo;
  xo.x = C1 * xv.x + C2 * (yv.x * r * ag);
  xo.y = C1 * xv.y + C2 * (yv.y * r * ag);
  xo.z = C1 * xv.z + C2 * (yv.z * r * ag);
  xo.w = C1 * xv.w + C2 * (yv.w * r * ag);
  bh4 x1o;
  x1o[0] = (bf16_t)xo.x; x1o[1] = (bf16_t)xo.y; x1o[2] = (bf16_t)xo.z; x1o[3] = (bf16_t)xo.w;
  *(bh4*)(x1 + (size_t)row * 1024 + t * 4) = x1o;
  float ss1 = xo.x*xo.x + xo.y*xo.y + xo.z*xo.z + xo.w*xo.w;
  float tot1 = block_sum(ss1, sbuf);
  float r1 = rsqrtf(tot1 * (1.f/1024.f) + 1e-4f);
  float4 g  = ((const float4*)(gs + b * 2048))[t];
  float4 sh = ((const float4*)(gs + b * 2048 + 1024))[t];
  bh4 o;
  o[0] = (bf16_t)(xo.x * r1 * (1.f + g.x) + sh.x);
  o[1] = (bf16_t)(xo.y * r1 * (1.f + g.y) + sh.y);
  o[2] = (bf16_t)(xo.z * r1 * (1.f + g.z) + sh.z);
  o[3] = (bf16_t)(xo.w * r1 * (1.f + g.w) + sh.w);
  *(bh4*)(xc2 + (size_t)row * 1024 + t * 4) = o;
}

// ---------- h = bf16(mp_silu(pixel_norm(hf))) over 4096-wide rows, bf16 in ----------
__global__ void k_mlpnorm(const bf16_t* __restrict__ hf, bf16_t* __restrict__ hb) {
  __shared__ float sbuf[4];
  int row = blockIdx.x, t = threadIdx.x;
  const bf16_t* rp = hf + (size_t)row * 4096;
  float4 v[4]; float ss = 0.f;
#pragma unroll
  for (int i = 0; i < 4; i++) {
    bh4 bv = *(const bh4*)(rp + (t + 256 * i) * 4);
    v[i].x = (float)bv[0]; v[i].y = (float)bv[1]; v[i].z = (float)bv[2]; v[i].w = (float)bv[3];
    ss += v[i].x*v[i].x + v[i].y*v[i].y + v[i].z*v[i].z + v[i].w*v[i].w;
  }
  float tot = block_sum(ss, sbuf);
  float r = rsqrtf(tot * (1.f/4096.f) + 1e-4f);
#pragma unroll
  for (int i = 0; i < 4; i++) {
    float a[4] = {v[i].x, v[i].y, v[i].z, v[i].w};
    bh4 o;
#pragma unroll
    for (int j = 0; j < 4; j++) {
      float u = a[j] * r;
      float sig = 1.f / (1.f + __expf(-u));
      o[j] = (bf16_t)(u * sig * (1.f / 0.596f));
    }
    *(bh4*)(hb + (size_t)row * 4096 + (t + 256 * i) * 4) = o;
  }
}

// ---------- out = mp_add(x1, pixel_norm(y0+y1+y2+y3)*exp(mg)) ----------
__global__ void k_fmerge(const bf16_t* __restrict__ y, const bf16_t* __restrict__ x1,
                         const float* __restrict__ mgain, float* __restrict__ out) {
  __shared__ float sbuf[4];
  int row = blockIdx.x, t = threadIdx.x;
  const size_t PS = (size_t)4096 * 1024;
  float4 yv = {0.f, 0.f, 0.f, 0.f};
#pragma unroll
  for (int p = 0; p < 4; p++) {
    bh4 yp = *(const bh4*)(y + p * PS + (size_t)row * 1024 + t * 4);
    yv.x += (float)yp[0]; yv.y += (float)yp[1]; yv.z += (float)yp[2]; yv.w += (float)yp[3];
  }
  bh4 xb = *(const bh4*)(x1 + (size_t)row * 1024 + t * 4);
  float4 xv = {(float)xb[0], (float)xb[1], (float)xb[2], (float)xb[3]};
  float ss = yv.x*yv.x + yv.y*yv.y + yv.z*yv.z + yv.w*yv.w;
  float tot = block_sum(ss, sbuf);
  float r = rsqrtf(tot * (1.f/1024.f) + 1e-4f);
  float mg = __expf(mgain[0]);
  const float C1 = 0.7f / 0.76157731059f, C2 = 0.3f / 0.76157731059f;
  float4 o;
  o.x = C1 * xv.x + C2 * (yv.x * r * mg);
  o.y = C1 * xv.y + C2 * (yv.y * r * mg);
  o.z = C1 * xv.z + C2 * (yv.z * r * mg);
  o.w = C1 * xv.w + C2 * (yv.w * r * mg);
  ((float4*)(out + (size_t)row * 1024))[t] = o;
}

// ---------- launch ----------
extern "C" void kernel_launch(void* const* d_in, const int* in_sizes, int n_in,
                              void* d_out, int out_size, void* d_ws, size_t ws_size,
                              hipStream_t stream) {
  const float* x      = (const float*)d_in[0];
  const float* c      = (const float*)d_in[1];
  const float* w_cond = (const float*)d_in[2];
  const float* w_qkv  = (const float*)d_in[3];
  const float* w_out  = (const float*)d_in[4];
  const float* w_mlp1 = (const float*)d_in[5];
  const float* w_mlp2 = (const float*)d_in[6];
  const float* again  = (const float*)d_in[7];
  const float* mgain  = (const float*)d_in[8];
  float* out = (float*)d_out;
  char* ws = (char*)d_ws;

  // ws layout (bytes)
  bf16_t* wt_cond = (bf16_t*)(ws + 0);                    //  4 MB [2048,1024]
  bf16_t* wt_qkv  = (bf16_t*)(ws + 4194304);              //  6 MB [3072,1024]
  bf16_t* wt_out  = (bf16_t*)(ws + 10485760);             //  2 MB [1024,1024]
  bf16_t* wt_mlp1 = (bf16_t*)(ws + 12582912);             //  8 MB [4096,1024]
  bf16_t* wt_mlp2 = (bf16_t*)(ws + 20971520);             //  8 MB [1024,4096]
  float*  sn      = (float*)(ws + 29360128);              //  32 KB (5 scale arrays, packed)
  float*  gs      = (float*)(ws + 29392896);              //  32 KB [4,2048]
  bf16_t* xc      = (bf16_t*)(ws + 29425664);             //  8 MB (xc, later xc2)
  bf16_t* qh      = (bf16_t*)(ws + 37814272);             //  8 MB
  bf16_t* kh      = (bf16_t*)(ws + 46202880);             //  8 MB
  bf16_t* vh      = (bf16_t*)(ws + 54591488);             //  8 MB
  bf16_t* xattn   = (bf16_t*)(ws + 62980096);             //  8 MB
  bf16_t* hb      = (bf16_t*)(ws + 37814272);             // 32 MB = qh..xattn reused after consumed
  bf16_t* x1      = (bf16_t*)(ws + 71368704);             //  8 MB (bf16 residual)
  bf16_t* buf_b   = (bf16_t*)(ws + 88145920);             // 32 MB bf16: qkv / y2(x2) / h / y4(x4)

  // weight prep (re-done every call: ws is re-poisoned by harness)
  k_wnorm_all<<<8192, 256, 0, stream>>>(w_cond, w_qkv, w_out, w_mlp1, w_mlp2, sn);
  k_wtrans_all<<<3584, 256, 0, stream>>>(w_cond, w_qkv, w_out, w_mlp1, w_mlp2, sn,
                                         wt_cond, wt_qkv, wt_out, wt_mlp1, wt_mlp2);

  // conditioning
  k_cond<<<512, 256, 0, stream>>>(c, wt_cond, gs);
  // attention branch
  k_xcond<<<4096, 256, 0, stream>>>(x, gs, xc);
  k_gemm<<<dim3(24, 32, 1), 256, 0, stream>>>(xc, wt_qkv, buf_b, 4096, 3072, 1024, 1024);
  k_qkvnorm<<<4096, 256, 0, stream>>>(buf_b, qh, kh, vh);
  k_attn<<<dim3(8, 64), 256, 0, stream>>>(qh, kh, vh, xattn);
  k_gemm<<<dim3(8, 32, 2), 256, 0, stream>>>(xattn, wt_out, buf_b, 4096, 1024, 1024, 512);
  k_amerge<<<4096, 256, 0, stream>>>(buf_b, x, gs, again, x1, xc);
  // MLP branch
  k_gemm<<<dim3(32, 32, 1), 256, 0, stream>>>(xc, wt_mlp1, buf_b, 4096, 4096, 1024, 1024);
  k_mlpnorm<<<4096, 256, 0, stream>>>(buf_b, hb);
  k_gemm<<<dim3(8, 32, 4), 256, 0, stream>>>(hb, wt_mlp2, buf_b, 4096, 1024, 4096, 1024);
  k_fmerge<<<4096, 256, 0, stream>>>(buf_b, x1, mgain, out);
  (void)in_sizes; (void)n_in; (void)out_size; (void)ws_size;
}

// Round 5
// 402.056 us; speedup vs baseline: 1.0596x; 1.0596x over previous
//
#include <hip/hip_runtime.h>

typedef __bf16 bf16_t;
typedef __attribute__((ext_vector_type(8))) __bf16 bh8;
typedef __attribute__((ext_vector_type(4))) __bf16 bh4;
typedef __attribute__((ext_vector_type(4))) float f32x4;

#define DEV static __device__ __forceinline__

typedef __attribute__((address_space(3))) void lds_void;
typedef const __attribute__((address_space(1))) void glb_void;

// async global->LDS, 16B per lane; LDS dest = wave-uniform base + lane*16
DEV void async16(const bf16_t* g, bf16_t* l) {
  __builtin_amdgcn_global_load_lds((glb_void*)g, (lds_void*)l, 16, 0, 0);
}

// ---------- helpers ----------
DEV float wave_sum(float v) {
#pragma unroll
  for (int m = 32; m > 0; m >>= 1) v += __shfl_xor(v, m, 64);
  return v;
}

// assumes blockDim.x == 256 (4 waves)
DEV float block_sum(float v, float* sbuf) {
  v = wave_sum(v);
  int wid = threadIdx.x >> 6;
  if ((threadIdx.x & 63) == 0) sbuf[wid] = v;
  __syncthreads();
  float r = sbuf[0] + sbuf[1] + sbuf[2] + sbuf[3];
  __syncthreads();
  return r;
}

// ---------- fused weight-row norms: all 5 weights in one dispatch ----------
// s layout: [0:1024) cond, [1024:2048) qkv, [2048:3072) out, [3072:4096) mlp1, [4096:8192) mlp2
__global__ void k_wnorm_all(const float* __restrict__ w_cond, const float* __restrict__ w_qkv,
                            const float* __restrict__ w_out, const float* __restrict__ w_mlp1,
                            const float* __restrict__ w_mlp2, float* __restrict__ s) {
  __shared__ float sbuf[4];
  int id = blockIdx.x;
  const float* W; int N, K, row;
  if (id < 1024)      { W = w_cond; N = 2048; K = 1024; row = id; }
  else if (id < 2048) { W = w_qkv;  N = 3072; K = 1024; row = id - 1024; }
  else if (id < 3072) { W = w_out;  N = 1024; K = 1024; row = id - 2048; }
  else if (id < 4096) { W = w_mlp1; N = 4096; K = 1024; row = id - 3072; }
  else                { W = w_mlp2; N = 1024; K = 4096; row = id - 4096; }
  const float4* wr = (const float4*)(W + (size_t)row * N);
  float acc = 0.f;
  for (int i = threadIdx.x; i < (N >> 2); i += 256) {
    float4 w = wr[i];
    acc += w.x*w.x + w.y*w.y + w.z*w.z + w.w*w.w;
  }
  float tot = block_sum(acc, sbuf);
  if (threadIdx.x == 0) {
    float norm = sqrtf(tot);
    s[id] = 1.0f / ((norm * sqrtf((float)N) + 1e-4f) * sqrtf((float)K));
  }
}

// ---------- fused transpose+scale+cast: Wt[n][k] = bf16(W[k][n]*s[k]) ----------
__global__ void k_wtrans_all(const float* __restrict__ w_cond, const float* __restrict__ w_qkv,
                             const float* __restrict__ w_out, const float* __restrict__ w_mlp1,
                             const float* __restrict__ w_mlp2, const float* __restrict__ sall,
                             bf16_t* __restrict__ wt_cond, bf16_t* __restrict__ wt_qkv,
                             bf16_t* __restrict__ wt_out, bf16_t* __restrict__ wt_mlp1,
                             bf16_t* __restrict__ wt_mlp2) {
  __shared__ float tile[64][65];
  int id = blockIdx.x;
  const float* W; const float* s; bf16_t* Wt; int K, N, n0, k0;
  if (id < 512)       { W=w_cond; s=sall;      Wt=wt_cond; K=1024; N=2048; int l=id;      n0=(l&31)*64; k0=(l>>5)*64; }
  else if (id < 1280) { W=w_qkv;  s=sall+1024; Wt=wt_qkv;  K=1024; N=3072; int l=id-512;  n0=(l%48)*64; k0=(l/48)*64; }
  else if (id < 1536) { W=w_out;  s=sall+2048; Wt=wt_out;  K=1024; N=1024; int l=id-1280; n0=(l&15)*64; k0=(l>>4)*64; }
  else if (id < 2560) { W=w_mlp1; s=sall+3072; Wt=wt_mlp1; K=1024; N=4096; int l=id-1536; n0=(l&63)*64; k0=(l>>6)*64; }
  else                { W=w_mlp2; s=sall+4096; Wt=wt_mlp2; K=4096; N=1024; int l=id-2560; n0=(l&15)*64; k0=(l>>4)*64; }
  int tx = threadIdx.x & 63, ty = threadIdx.x >> 6;
  for (int r = ty; r < 64; r += 4)
    tile[r][tx] = W[(size_t)(k0 + r) * N + n0 + tx] * s[k0 + r];
  __syncthreads();
  for (int r = ty; r < 64; r += 4)
    Wt[(size_t)(n0 + r) * K + k0 + tx] = (bf16_t)tile[tx][r];
}

// ---------- conditioning: gs[b][j] = (silu(c[b])/0.596) . wn_cond[:,j] ----------
__global__ void k_cond(const float* __restrict__ c, const bf16_t* __restrict__ wt,
                       float* __restrict__ gs) {
  __shared__ float cc[4][1024];
  int t = threadIdx.x;
  for (int i = t; i < 4096; i += 256) {
    int b = i >> 10, col = i & 1023;
    float x = c[b * 1024 + col];
    float sig = 1.f / (1.f + __expf(-x));
    cc[b][col] = x * sig * (1.f / 0.596f);
  }
  __syncthreads();
  int wid = t >> 6, lane = t & 63;
  int j = blockIdx.x * 4 + wid;
  const bf16_t* wr = wt + (size_t)j * 1024;
  float acc0 = 0, acc1 = 0, acc2 = 0, acc3 = 0;
  for (int i = lane; i < 1024; i += 64) {
    float w = (float)wr[i];
    acc0 += cc[0][i] * w; acc1 += cc[1][i] * w;
    acc2 += cc[2][i] * w; acc3 += cc[3][i] * w;
  }
  float v0 = wave_sum(acc0), v1 = wave_sum(acc1), v2 = wave_sum(acc2), v3 = wave_sum(acc3);
  if (lane == 0) {
    gs[0 * 2048 + j] = v0; gs[1 * 2048 + j] = v1;
    gs[2 * 2048 + j] = v2; gs[3 * 2048 + j] = v3;
  }
}

// ---------- xc = bf16(pixel_norm(x)*(1+gain)+shift), one block per row ----------
__global__ void k_xcond(const float* __restrict__ x, const float* __restrict__ gs,
                        bf16_t* __restrict__ xc) {
  __shared__ float sbuf[4];
  int row = blockIdx.x, b = row >> 10, t = threadIdx.x;
  float4 v = ((const float4*)(x + (size_t)row * 1024))[t];
  float ss = v.x*v.x + v.y*v.y + v.z*v.z + v.w*v.w;
  float tot = block_sum(ss, sbuf);
  float r = rsqrtf(tot * (1.f/1024.f) + 1e-4f);
  float4 g  = ((const float4*)(gs + b * 2048))[t];
  float4 sh = ((const float4*)(gs + b * 2048 + 1024))[t];
  bh4 o;
  o[0] = (bf16_t)(v.x * r * (1.f + g.x) + sh.x);
  o[1] = (bf16_t)(v.y * r * (1.f + g.y) + sh.y);
  o[2] = (bf16_t)(v.z * r * (1.f + g.z) + sh.z);
  o[3] = (bf16_t)(v.w * r * (1.f + g.w) + sh.w);
  *(bh4*)(xc + (size_t)row * 1024 + t * 4) = o;
}

// ---------- bf16 MFMA GEMM, BK=64 (half the barriers of BK=32) ----------
// grid.z = split-K index; C offset by z*M*N; klen = K per split.
// LDS = two [128][32] half-tiles per operand (same 64B row stride as the
// verified BK=32 layout -> identical bank behavior, lane-linear staging).
__global__ __launch_bounds__(256) void k_gemm(const bf16_t* __restrict__ A,
                                              const bf16_t* __restrict__ Bt,
                                              bf16_t* __restrict__ C,
                                              int M, int N, int K, int klen) {
  __shared__ bf16_t As[2][128][32];
  __shared__ bf16_t Bs[2][128][32];
  const unsigned gx = gridDim.x;
  const unsigned flat = blockIdx.x + gx * blockIdx.y;
  const unsigned npx = gx >> 3;
  const unsigned xcd = flat & 7, o = flat >> 3;
  const unsigned grp = npx * 8;
  const unsigned mg = o / grp, rr = o % grp;
  const int m0 = (mg * 8 + rr / npx) * 128;
  const int n0 = (xcd * npx + rr % npx) * 128;
  const size_t kbeg = (size_t)blockIdx.z * klen;
  C += (size_t)blockIdx.z * M * N;
  const int t = threadIdx.x, lane = t & 63, wid = t >> 6;
  const int l15 = lane & 15, quad = lane >> 4;
  const int wm = (wid >> 1) * 64, wn = (wid & 1) * 64;
  const int r0 = t >> 2, kc0 = (t & 3) * 8;
  const bf16_t* Ag0 = A + (size_t)(m0 + r0) * K + kbeg + kc0;
  const bf16_t* Bg0 = Bt + (size_t)(n0 + r0) * K + kbeg + kc0;
  bf16_t* lA0 = &As[0][0][0] + wid * 512;   // wave-uniform LDS dest
  bf16_t* lB0 = &Bs[0][0][0] + wid * 512;
  f32x4 acc[4][4] = {};
  for (int k0 = 0; k0 < klen; k0 += 64) {
#pragma unroll
    for (int h = 0; h < 2; h++) {
      async16(Ag0 + k0 + h * 32, lA0 + h * 4096);
      async16(Ag0 + k0 + h * 32 + (size_t)64 * K, lA0 + h * 4096 + 2048);
      async16(Bg0 + k0 + h * 32, lB0 + h * 4096);
      async16(Bg0 + k0 + h * 32 + (size_t)64 * K, lB0 + h * 4096 + 2048);
    }
    __syncthreads();
#pragma unroll
    for (int h = 0; h < 2; h++) {
      bh8 a[4], bb[4];
#pragma unroll
      for (int i = 0; i < 4; i++) a[i]  = *(const bh8*)&As[h][wm + i*16 + l15][quad*8];
#pragma unroll
      for (int j = 0; j < 4; j++) bb[j] = *(const bh8*)&Bs[h][wn + j*16 + l15][quad*8];
#pragma unroll
      for (int i = 0; i < 4; i++)
#pragma unroll
        for (int j = 0; j < 4; j++)
          acc[i][j] = __builtin_amdgcn_mfma_f32_16x16x32_bf16(a[i], bb[j], acc[i][j], 0, 0, 0);
    }
    __syncthreads();
  }
#pragma unroll
  for (int i = 0; i < 4; i++)
#pragma unroll
    for (int j = 0; j < 4; j++)
#pragma unroll
      for (int r2 = 0; r2 < 4; r2++)
        C[(size_t)(m0 + wm + i*16 + quad*4 + r2) * N + n0 + wn + j*16 + l15] =
            (bf16_t)acc[i][j][r2];
}

// ---------- qkv (bf16 in): pixel_norm per 1024-chunk + per-head L2 norm; write [B,NH,N,DH] ----------
__global__ void k_qkvnorm(const bf16_t* __restrict__ qkv, bf16_t* __restrict__ qo,
                          bf16_t* __restrict__ ko, bf16_t* __restrict__ vo) {
  __shared__ float sbuf[4];
  const int row = blockIdx.x, b = row >> 10, n = row & 1023, t = threadIdx.x;
  const bf16_t* rp = qkv + (size_t)row * 3072;
  bh4 q4 = *(const bh4*)(rp + t * 4);
  bh4 k4 = *(const bh4*)(rp + 1024 + t * 4);
  bh4 v4 = *(const bh4*)(rp + 2048 + t * 4);
  float4 q = {(float)q4[0], (float)q4[1], (float)q4[2], (float)q4[3]};
  float4 k = {(float)k4[0], (float)k4[1], (float)k4[2], (float)k4[3]};
  float4 v = {(float)v4[0], (float)v4[1], (float)v4[2], (float)v4[3]};
  float sq = q.x*q.x + q.y*q.y + q.z*q.z + q.w*q.w;
  float sk = k.x*k.x + k.y*k.y + k.z*k.z + k.w*k.w;
  float sv = v.x*v.x + v.y*v.y + v.z*v.z + v.w*v.w;
  float tq = block_sum(sq, sbuf);
  float tk = block_sum(sk, sbuf);
  float tv = block_sum(sv, sbuf);
  float rq = rsqrtf(tq * (1.f/1024.f) + 1e-4f);
  float rk = rsqrtf(tk * (1.f/1024.f) + 1e-4f);
  float rv = rsqrtf(tv * (1.f/1024.f) + 1e-4f);
  float hq = sq, hk = sk;   // per-head sums: 16 consecutive threads = one head (within a wave)
#pragma unroll
  for (int m = 1; m < 16; m <<= 1) { hq += __shfl_xor(hq, m, 64); hk += __shfl_xor(hk, m, 64); }
  float qs = rq * rsqrtf(rq*rq*hq + 1e-6f);
  float ks = rk * rsqrtf(rk*rk*hk + 1e-6f);
  int h = t >> 4, d = (t & 15) * 4;
  size_t base = ((size_t)(b * 16 + h) * 1024 + n) * 64 + d;
  bh4 oq, okk, ov;
  oq[0]=(bf16_t)(q.x*qs); oq[1]=(bf16_t)(q.y*qs); oq[2]=(bf16_t)(q.z*qs); oq[3]=(bf16_t)(q.w*qs);
  okk[0]=(bf16_t)(k.x*ks); okk[1]=(bf16_t)(k.y*ks); okk[2]=(bf16_t)(k.z*ks); okk[3]=(bf16_t)(k.w*ks);
  ov[0]=(bf16_t)(v.x*rv); ov[1]=(bf16_t)(v.y*rv); ov[2]=(bf16_t)(v.z*rv); ov[3]=(bf16_t)(v.w*rv);
  *(bh4*)(qo + base) = oq;
  *(bh4*)(ko + base) = okk;
  *(bh4*)(vo + base) = ov;
}

// ---------- attention, Q-tile 64 (36 KB LDS -> 4 blocks/CU) ----------
// scores bounded in [-1/8,1/8] -> no max-subtraction needed
__global__ __launch_bounds__(256) void k_attn(const bf16_t* __restrict__ Q,
                                              const bf16_t* __restrict__ K,
                                              const bf16_t* __restrict__ V,
                                              bf16_t* __restrict__ O) {
  __shared__ bf16_t Qs[64][72];
  __shared__ bf16_t Ks[64][72];
  __shared__ bf16_t Vt[64][72];   // Vt[dh][kv]
  __shared__ bf16_t Ps[64][72];
  const int qt = blockIdx.x, bh = blockIdx.y;
  const int b = bh >> 4, h = bh & 15;
  const int t = threadIdx.x, lane = t & 63, wid = t >> 6;
  const int l15 = lane & 15, quad = lane >> 4;
  const int strip = wid * 16;
  const bf16_t* Qg = Q + ((size_t)bh * 1024 + qt * 64) * 64;
  const bf16_t* Kg = K + (size_t)bh * 1024 * 64;
  const bf16_t* Vg = V + (size_t)bh * 1024 * 64;
  for (int i = t; i < 512; i += 256) {
    int r = i >> 3, p = (i & 7) * 8;
    *(bh8*)&Qs[r][p] = *(const bh8*)(Qg + r * 64 + p);
  }
  f32x4 o[4] = {};
  float rs[4] = {};
  __syncthreads();
  for (int kv0 = 0; kv0 < 1024; kv0 += 64) {
    for (int i = t; i < 512; i += 256) {
      int r = i >> 3, p = (i & 7) * 8;
      *(bh8*)&Ks[r][p] = *(const bh8*)(Kg + (size_t)(kv0 + r) * 64 + p);
      bh8 vv = *(const bh8*)(Vg + (size_t)(kv0 + r) * 64 + p);
#pragma unroll
      for (int j = 0; j < 8; j++) Vt[p + j][r] = vv[j];
    }
    __syncthreads();
    // S = Q Kt for this wave's 16-row strip
    f32x4 s[4] = {};
#pragma unroll
    for (int kc = 0; kc < 2; kc++) {
      bh8 aq = *(const bh8*)&Qs[strip + l15][kc*32 + quad*8];
      bh8 bk[4];
#pragma unroll
      for (int j = 0; j < 4; j++) bk[j] = *(const bh8*)&Ks[j*16 + l15][kc*32 + quad*8];
#pragma unroll
      for (int j = 0; j < 4; j++)
        s[j] = __builtin_amdgcn_mfma_f32_16x16x32_bf16(aq, bk[j], s[j], 0, 0, 0);
    }
    // P = exp(S/8); accumulate per-lane rowsums; C-layout -> LDS -> A-layout
#pragma unroll
    for (int j = 0; j < 4; j++)
#pragma unroll
      for (int r = 0; r < 4; r++) {
        float p = __expf(s[j][r] * 0.125f);
        bf16_t pb = (bf16_t)p;
        rs[r] += (float)pb;   // keep rs consistent with bf16 P fed to PV
        Ps[strip + quad*4 + r][j*16 + l15] = pb;
      }
    // O += P @ V  (wave reads only its own Ps strip -> no extra barrier needed)
#pragma unroll
    for (int kc = 0; kc < 2; kc++) {
      bh8 ap = *(const bh8*)&Ps[strip + l15][kc*32 + quad*8];
      bh8 bv[4];
#pragma unroll
      for (int j = 0; j < 4; j++) bv[j] = *(const bh8*)&Vt[j*16 + l15][kc*32 + quad*8];
#pragma unroll
      for (int j = 0; j < 4; j++)
        o[j] = __builtin_amdgcn_mfma_f32_16x16x32_bf16(ap, bv[j], o[j], 0, 0, 0);
    }
    __syncthreads();
  }
  // finalize rowsums: sum across the 16 column-lanes of each quad; O rows match rs rows
#pragma unroll
  for (int r = 0; r < 4; r++) {
    float v = rs[r];
    v += __shfl_xor(v, 1, 64); v += __shfl_xor(v, 2, 64);
    v += __shfl_xor(v, 4, 64); v += __shfl_xor(v, 8, 64);
    float inv = 1.f / v;
    int n = qt * 64 + strip + quad*4 + r;
#pragma unroll
    for (int j = 0; j < 4; j++)
      O[((size_t)b * 1024 + n) * 1024 + h*64 + j*16 + l15] = (bf16_t)(o[j][r] * inv);
  }
}

// ---------- x1 = mp_add(x, pixel_norm(y0+y1)*exp(ag)) [bf16 out]; xc2 = bf16(pixel_norm(x1)*(1+g)+s) ----------
__global__ void k_amerge(const bf16_t* __restrict__ y, const float* __restrict__ x,
                         const float* __restrict__ gs, const float* __restrict__ again,
                         bf16_t* __restrict__ x1, bf16_t* __restrict__ xc2) {
  __shared__ float sbuf[4];
  int row = blockIdx.x, b = row >> 10, t = threadIdx.x;
  const size_t PS = (size_t)4096 * 1024;   // split-K partial stride (elements)
  bh4 a0 = *(const bh4*)(y + (size_t)row * 1024 + t * 4);
  bh4 a1 = *(const bh4*)(y + PS + (size_t)row * 1024 + t * 4);
  float4 yv;
  yv.x = (float)a0[0] + (float)a1[0]; yv.y = (float)a0[1] + (float)a1[1];
  yv.z = (float)a0[2] + (float)a1[2]; yv.w = (float)a0[3] + (float)a1[3];
  float4 xv = ((const float4*)(x + (size_t)row * 1024))[t];
  float ss = yv.x*yv.x + yv.y*yv.y + yv.z*yv.z + yv.w*yv.w;
  float tot = block_sum(ss, sbuf);
  float r = rsqrtf(tot * (1.f/1024.f) + 1e-4f);
  float ag = __expf(again[0]);
  const float C1 = 0.7f / 0.76157731059f, C2 = 0.3f / 0.76157731059f; // /sqrt(0.58)
  float4 xo;
  xo.x = C1 * xv.x + C2 * (yv.x * r * ag);
  xo.y = C1 * xv.y + C2 * (yv.y * r * ag);
  xo.z = C1 * xv.z + C2 * (yv.z * r * ag);
  xo.w = C1 * xv.w + C2 * (yv.w * r * ag);
  bh4 x1o;
  x1o[0] = (bf16_t)xo.x; x1o[1] = (bf16_t)xo.y; x1o[2] = (bf16_t)xo.z; x1o[3] = (bf16_t)xo.w;
  *(bh4*)(x1 + (size_t)row * 1024 + t * 4) = x1o;
  float ss1 = xo.x*xo.x + xo.y*xo.y + xo.z*xo.z + xo.w*xo.w;
  float tot1 = block_sum(ss1, sbuf);
  float r1 = rsqrtf(tot1 * (1.f/1024.f) + 1e-4f);
  float4 g  = ((const float4*)(gs + b * 2048))[t];
  float4 sh = ((const float4*)(gs + b * 2048 + 1024))[t];
  bh4 o;
  o[0] = (bf16_t)(xo.x * r1 * (1.f + g.x) + sh.x);
  o[1] = (bf16_t)(xo.y * r1 * (1.f + g.y) + sh.y);
  o[2] = (bf16_t)(xo.z * r1 * (1.f + g.z) + sh.z);
  o[3] = (bf16_t)(xo.w * r1 * (1.f + g.w) + sh.w);
  *(bh4*)(xc2 + (size_t)row * 1024 + t * 4) = o;
}

// ---------- h = bf16(mp_silu(pixel_norm(hf))) over 4096-wide rows, bf16 in ----------
__global__ void k_mlpnorm(const bf16_t* __restrict__ hf, bf16_t* __restrict__ hb) {
  __shared__ float sbuf[4];
  int row = blockIdx.x, t = threadIdx.x;
  const bf16_t* rp = hf + (size_t)row * 4096;
  float4 v[4]; float ss = 0.f;
#pragma unroll
  for (int i = 0; i < 4; i++) {
    bh4 bv = *(const bh4*)(rp + (t + 256 * i) * 4);
    v[i].x = (float)bv[0]; v[i].y = (float)bv[1]; v[i].z = (float)bv[2]; v[i].w = (float)bv[3];
    ss += v[i].x*v[i].x + v[i].y*v[i].y + v[i].z*v[i].z + v[i].w*v[i].w;
  }
  float tot = block_sum(ss, sbuf);
  float r = rsqrtf(tot * (1.f/4096.f) + 1e-4f);
#pragma unroll
  for (int i = 0; i < 4; i++) {
    float a[4] = {v[i].x, v[i].y, v[i].z, v[i].w};
    bh4 o;
#pragma unroll
    for (int j = 0; j < 4; j++) {
      float u = a[j] * r;
      float sig = 1.f / (1.f + __expf(-u));
      o[j] = (bf16_t)(u * sig * (1.f / 0.596f));
    }
    *(bh4*)(hb + (size_t)row * 4096 + (t + 256 * i) * 4) = o;
  }
}

// ---------- out = mp_add(x1, pixel_norm(y0+y1)*exp(mg)) ----------
__global__ void k_fmerge(const bf16_t* __restrict__ y, const bf16_t* __restrict__ x1,
                         const float* __restrict__ mgain, float* __restrict__ out) {
  __shared__ float sbuf[4];
  int row = blockIdx.x, t = threadIdx.x;
  const size_t PS = (size_t)4096 * 1024;
  float4 yv = {0.f, 0.f, 0.f, 0.f};
#pragma unroll
  for (int p = 0; p < 2; p++) {
    bh4 yp = *(const bh4*)(y + p * PS + (size_t)row * 1024 + t * 4);
    yv.x += (float)yp[0]; yv.y += (float)yp[1]; yv.z += (float)yp[2]; yv.w += (float)yp[3];
  }
  bh4 xb = *(const bh4*)(x1 + (size_t)row * 1024 + t * 4);
  float4 xv = {(float)xb[0], (float)xb[1], (float)xb[2], (float)xb[3]};
  float ss = yv.x*yv.x + yv.y*yv.y + yv.z*yv.z + yv.w*yv.w;
  float tot = block_sum(ss, sbuf);
  float r = rsqrtf(tot * (1.f/1024.f) + 1e-4f);
  float mg = __expf(mgain[0]);
  const float C1 = 0.7f / 0.76157731059f, C2 = 0.3f / 0.76157731059f;
  float4 o;
  o.x = C1 * xv.x + C2 * (yv.x * r * mg);
  o.y = C1 * xv.y + C2 * (yv.y * r * mg);
  o.z = C1 * xv.z + C2 * (yv.z * r * mg);
  o.w = C1 * xv.w + C2 * (yv.w * r * mg);
  ((float4*)(out + (size_t)row * 1024))[t] = o;
}

// ---------- launch ----------
extern "C" void kernel_launch(void* const* d_in, const int* in_sizes, int n_in,
                              void* d_out, int out_size, void* d_ws, size_t ws_size,
                              hipStream_t stream) {
  const float* x      = (const float*)d_in[0];
  const float* c      = (const float*)d_in[1];
  const float* w_cond = (const float*)d_in[2];
  const float* w_qkv  = (const float*)d_in[3];
  const float* w_out  = (const float*)d_in[4];
  const float* w_mlp1 = (const float*)d_in[5];
  const float* w_mlp2 = (const float*)d_in[6];
  const float* again  = (const float*)d_in[7];
  const float* mgain  = (const float*)d_in[8];
  float* out = (float*)d_out;
  char* ws = (char*)d_ws;

  // ws layout (bytes)
  bf16_t* wt_cond = (bf16_t*)(ws + 0);                    //  4 MB [2048,1024]
  bf16_t* wt_qkv  = (bf16_t*)(ws + 4194304);              //  6 MB [3072,1024]
  bf16_t* wt_out  = (bf16_t*)(ws + 10485760);             //  2 MB [1024,1024]
  bf16_t* wt_mlp1 = (bf16_t*)(ws + 12582912);             //  8 MB [4096,1024]
  bf16_t* wt_mlp2 = (bf16_t*)(ws + 20971520);             //  8 MB [1024,4096]
  float*  sn      = (float*)(ws + 29360128);              //  32 KB (5 scale arrays, packed)
  float*  gs      = (float*)(ws + 29392896);              //  32 KB [4,2048]
  bf16_t* xc      = (bf16_t*)(ws + 29425664);             //  8 MB (xc, later xc2)
  bf16_t* qh      = (bf16_t*)(ws + 37814272);             //  8 MB
  bf16_t* kh      = (bf16_t*)(ws + 46202880);             //  8 MB
  bf16_t* vh      = (bf16_t*)(ws + 54591488);             //  8 MB
  bf16_t* xattn   = (bf16_t*)(ws + 62980096);             //  8 MB
  bf16_t* hb      = (bf16_t*)(ws + 37814272);             // 32 MB = qh..xattn reused after consumed
  bf16_t* x1      = (bf16_t*)(ws + 71368704);             //  8 MB (bf16 residual)
  bf16_t* buf_b   = (bf16_t*)(ws + 88145920);             // 32 MB bf16: qkv / y2(x2) / h / y4(x2)

  // weight prep (re-done every call: ws is re-poisoned by harness)
  k_wnorm_all<<<8192, 256, 0, stream>>>(w_cond, w_qkv, w_out, w_mlp1, w_mlp2, sn);
  k_wtrans_all<<<3584, 256, 0, stream>>>(w_cond, w_qkv, w_out, w_mlp1, w_mlp2, sn,
                                         wt_cond, wt_qkv, wt_out, wt_mlp1, wt_mlp2);

  // conditioning
  k_cond<<<512, 256, 0, stream>>>(c, wt_cond, gs);
  // attention branch
  k_xcond<<<4096, 256, 0, stream>>>(x, gs, xc);
  k_gemm<<<dim3(24, 32, 1), 256, 0, stream>>>(xc, wt_qkv, buf_b, 4096, 3072, 1024, 1024);
  k_qkvnorm<<<4096, 256, 0, stream>>>(buf_b, qh, kh, vh);
  k_attn<<<dim3(16, 64), 256, 0, stream>>>(qh, kh, vh, xattn);
  k_gemm<<<dim3(8, 32, 2), 256, 0, stream>>>(xattn, wt_out, buf_b, 4096, 1024, 1024, 512);
  k_amerge<<<4096, 256, 0, stream>>>(buf_b, x, gs, again, x1, xc);
  // MLP branch
  k_gemm<<<dim3(32, 32, 1), 256, 0, stream>>>(xc, wt_mlp1, buf_b, 4096, 4096, 1024, 1024);
  k_mlpnorm<<<4096, 256, 0, stream>>>(buf_b, hb);
  k_gemm<<<dim3(8, 32, 2), 256, 0, stream>>>(hb, wt_mlp2, buf_b, 4096, 1024, 4096, 2048);
  k_fmerge<<<4096, 256, 0, stream>>>(buf_b, x1, mgain, out);
  (void)in_sizes; (void)n_in; (void)out_size; (void)ws_size;
}

// Round 6
// 387.915 us; speedup vs baseline: 1.0983x; 1.0365x over previous
//
#include <hip/hip_runtime.h>

typedef __bf16 bf16_t;
typedef __attribute__((ext_vector_type(8))) __bf16 bh8;
typedef __attribute__((ext_vector_type(4))) __bf16 bh4;
typedef __attribute__((ext_vector_type(4))) float f32x4;

#define DEV static __device__ __forceinline__

typedef __attribute__((address_space(3))) void lds_void;
typedef const __attribute__((address_space(1))) void glb_void;

// async global->LDS, 16B per lane; LDS dest = wave-uniform base + lane*16
DEV void async16(const bf16_t* g, bf16_t* l) {
  __builtin_amdgcn_global_load_lds((glb_void*)g, (lds_void*)l, 16, 0, 0);
}

// ---------- helpers ----------
DEV float wave_sum(float v) {
#pragma unroll
  for (int m = 32; m > 0; m >>= 1) v += __shfl_xor(v, m, 64);
  return v;
}

// assumes blockDim.x == 256 (4 waves)
DEV float block_sum(float v, float* sbuf) {
  v = wave_sum(v);
  int wid = threadIdx.x >> 6;
  if ((threadIdx.x & 63) == 0) sbuf[wid] = v;
  __syncthreads();
  float r = sbuf[0] + sbuf[1] + sbuf[2] + sbuf[3];
  __syncthreads();
  return r;
}

// ---------- fused weight-row norms: all 5 weights in one dispatch ----------
// s layout: [0:1024) cond, [1024:2048) qkv, [2048:3072) out, [3072:4096) mlp1, [4096:8192) mlp2
__global__ void k_wnorm_all(const float* __restrict__ w_cond, const float* __restrict__ w_qkv,
                            const float* __restrict__ w_out, const float* __restrict__ w_mlp1,
                            const float* __restrict__ w_mlp2, float* __restrict__ s) {
  __shared__ float sbuf[4];
  int id = blockIdx.x;
  const float* W; int N, K, row;
  if (id < 1024)      { W = w_cond; N = 2048; K = 1024; row = id; }
  else if (id < 2048) { W = w_qkv;  N = 3072; K = 1024; row = id - 1024; }
  else if (id < 3072) { W = w_out;  N = 1024; K = 1024; row = id - 2048; }
  else if (id < 4096) { W = w_mlp1; N = 4096; K = 1024; row = id - 3072; }
  else                { W = w_mlp2; N = 1024; K = 4096; row = id - 4096; }
  const float4* wr = (const float4*)(W + (size_t)row * N);
  float acc = 0.f;
  for (int i = threadIdx.x; i < (N >> 2); i += 256) {
    float4 w = wr[i];
    acc += w.x*w.x + w.y*w.y + w.z*w.z + w.w*w.w;
  }
  float tot = block_sum(acc, sbuf);
  if (threadIdx.x == 0) {
    float norm = sqrtf(tot);
    s[id] = 1.0f / ((norm * sqrtf((float)N) + 1e-4f) * sqrtf((float)K));
  }
}

// ---------- fused transpose+scale+cast: Wt[n][k] = bf16(W[k][n]*s[k]) ----------
__global__ void k_wtrans_all(const float* __restrict__ w_cond, const float* __restrict__ w_qkv,
                             const float* __restrict__ w_out, const float* __restrict__ w_mlp1,
                             const float* __restrict__ w_mlp2, const float* __restrict__ sall,
                             bf16_t* __restrict__ wt_cond, bf16_t* __restrict__ wt_qkv,
                             bf16_t* __restrict__ wt_out, bf16_t* __restrict__ wt_mlp1,
                             bf16_t* __restrict__ wt_mlp2) {
  __shared__ float tile[64][65];
  int id = blockIdx.x;
  const float* W; const float* s; bf16_t* Wt; int K, N, n0, k0;
  if (id < 512)       { W=w_cond; s=sall;      Wt=wt_cond; K=1024; N=2048; int l=id;      n0=(l&31)*64; k0=(l>>5)*64; }
  else if (id < 1280) { W=w_qkv;  s=sall+1024; Wt=wt_qkv;  K=1024; N=3072; int l=id-512;  n0=(l%48)*64; k0=(l/48)*64; }
  else if (id < 1536) { W=w_out;  s=sall+2048; Wt=wt_out;  K=1024; N=1024; int l=id-1280; n0=(l&15)*64; k0=(l>>4)*64; }
  else if (id < 2560) { W=w_mlp1; s=sall+3072; Wt=wt_mlp1; K=1024; N=4096; int l=id-1536; n0=(l&63)*64; k0=(l>>6)*64; }
  else                { W=w_mlp2; s=sall+4096; Wt=wt_mlp2; K=4096; N=1024; int l=id-2560; n0=(l&15)*64; k0=(l>>4)*64; }
  int tx = threadIdx.x & 63, ty = threadIdx.x >> 6;
  for (int r = ty; r < 64; r += 4)
    tile[r][tx] = W[(size_t)(k0 + r) * N + n0 + tx] * s[k0 + r];
  __syncthreads();
  for (int r = ty; r < 64; r += 4)
    Wt[(size_t)(n0 + r) * K + k0 + tx] = (bf16_t)tile[tx][r];
}

// ---------- conditioning: gs[b][j] = (silu(c[b])/0.596) . wn_cond[:,j] ----------
__global__ void k_cond(const float* __restrict__ c, const bf16_t* __restrict__ wt,
                       float* __restrict__ gs) {
  __shared__ float cc[4][1024];
  int t = threadIdx.x;
  for (int i = t; i < 4096; i += 256) {
    int b = i >> 10, col = i & 1023;
    float x = c[b * 1024 + col];
    float sig = 1.f / (1.f + __expf(-x));
    cc[b][col] = x * sig * (1.f / 0.596f);
  }
  __syncthreads();
  int wid = t >> 6, lane = t & 63;
  int j = blockIdx.x * 4 + wid;
  const bf16_t* wr = wt + (size_t)j * 1024;
  float acc0 = 0, acc1 = 0, acc2 = 0, acc3 = 0;
  for (int i = lane; i < 1024; i += 64) {
    float w = (float)wr[i];
    acc0 += cc[0][i] * w; acc1 += cc[1][i] * w;
    acc2 += cc[2][i] * w; acc3 += cc[3][i] * w;
  }
  float v0 = wave_sum(acc0), v1 = wave_sum(acc1), v2 = wave_sum(acc2), v3 = wave_sum(acc3);
  if (lane == 0) {
    gs[0 * 2048 + j] = v0; gs[1 * 2048 + j] = v1;
    gs[2 * 2048 + j] = v2; gs[3 * 2048 + j] = v3;
  }
}

// ---------- xc = bf16(pixel_norm(x)*(1+gain)+shift), one block per row ----------
__global__ void k_xcond(const float* __restrict__ x, const float* __restrict__ gs,
                        bf16_t* __restrict__ xc) {
  __shared__ float sbuf[4];
  int row = blockIdx.x, b = row >> 10, t = threadIdx.x;
  float4 v = ((const float4*)(x + (size_t)row * 1024))[t];
  float ss = v.x*v.x + v.y*v.y + v.z*v.z + v.w*v.w;
  float tot = block_sum(ss, sbuf);
  float r = rsqrtf(tot * (1.f/1024.f) + 1e-4f);
  float4 g  = ((const float4*)(gs + b * 2048))[t];
  float4 sh = ((const float4*)(gs + b * 2048 + 1024))[t];
  bh4 o;
  o[0] = (bf16_t)(v.x * r * (1.f + g.x) + sh.x);
  o[1] = (bf16_t)(v.y * r * (1.f + g.y) + sh.y);
  o[2] = (bf16_t)(v.z * r * (1.f + g.z) + sh.z);
  o[3] = (bf16_t)(v.w * r * (1.f + g.w) + sh.w);
  *(bh4*)(xc + (size_t)row * 1024 + t * 4) = o;
}

// ---------- bf16 MFMA GEMM, BK=64 (half the barriers of BK=32) ----------
// grid.z = split-K index; C offset by z*M*N; klen = K per split.
// LDS = two [128][32] half-tiles per operand (same 64B row stride as the
// verified BK=32 layout -> identical bank behavior, lane-linear staging).
__global__ __launch_bounds__(256) void k_gemm(const bf16_t* __restrict__ A,
                                              const bf16_t* __restrict__ Bt,
                                              bf16_t* __restrict__ C,
                                              int M, int N, int K, int klen) {
  __shared__ bf16_t As[2][128][32];
  __shared__ bf16_t Bs[2][128][32];
  const unsigned gx = gridDim.x;
  const unsigned flat = blockIdx.x + gx * blockIdx.y;
  const unsigned npx = gx >> 3;
  const unsigned xcd = flat & 7, o = flat >> 3;
  const unsigned grp = npx * 8;
  const unsigned mg = o / grp, rr = o % grp;
  const int m0 = (mg * 8 + rr / npx) * 128;
  const int n0 = (xcd * npx + rr % npx) * 128;
  const size_t kbeg = (size_t)blockIdx.z * klen;
  C += (size_t)blockIdx.z * M * N;
  const int t = threadIdx.x, lane = t & 63, wid = t >> 6;
  const int l15 = lane & 15, quad = lane >> 4;
  const int wm = (wid >> 1) * 64, wn = (wid & 1) * 64;
  const int r0 = t >> 2, kc0 = (t & 3) * 8;
  const bf16_t* Ag0 = A + (size_t)(m0 + r0) * K + kbeg + kc0;
  const bf16_t* Bg0 = Bt + (size_t)(n0 + r0) * K + kbeg + kc0;
  bf16_t* lA0 = &As[0][0][0] + wid * 512;   // wave-uniform LDS dest
  bf16_t* lB0 = &Bs[0][0][0] + wid * 512;
  f32x4 acc[4][4] = {};
  for (int k0 = 0; k0 < klen; k0 += 64) {
#pragma unroll
    for (int h = 0; h < 2; h++) {
      async16(Ag0 + k0 + h * 32, lA0 + h * 4096);
      async16(Ag0 + k0 + h * 32 + (size_t)64 * K, lA0 + h * 4096 + 2048);
      async16(Bg0 + k0 + h * 32, lB0 + h * 4096);
      async16(Bg0 + k0 + h * 32 + (size_t)64 * K, lB0 + h * 4096 + 2048);
    }
    __syncthreads();
#pragma unroll
    for (int h = 0; h < 2; h++) {
      bh8 a[4], bb[4];
#pragma unroll
      for (int i = 0; i < 4; i++) a[i]  = *(const bh8*)&As[h][wm + i*16 + l15][quad*8];
#pragma unroll
      for (int j = 0; j < 4; j++) bb[j] = *(const bh8*)&Bs[h][wn + j*16 + l15][quad*8];
#pragma unroll
      for (int i = 0; i < 4; i++)
#pragma unroll
        for (int j = 0; j < 4; j++)
          acc[i][j] = __builtin_amdgcn_mfma_f32_16x16x32_bf16(a[i], bb[j], acc[i][j], 0, 0, 0);
    }
    __syncthreads();
  }
#pragma unroll
  for (int i = 0; i < 4; i++)
#pragma unroll
    for (int j = 0; j < 4; j++)
#pragma unroll
      for (int r2 = 0; r2 < 4; r2++)
        C[(size_t)(m0 + wm + i*16 + quad*4 + r2) * N + n0 + wn + j*16 + l15] =
            (bf16_t)acc[i][j][r2];
}

// ---------- qkv (bf16 in): pixel_norm per 1024-chunk + per-head L2 norm; write [B,NH,N,DH] ----------
__global__ void k_qkvnorm(const bf16_t* __restrict__ qkv, bf16_t* __restrict__ qo,
                          bf16_t* __restrict__ ko, bf16_t* __restrict__ vo) {
  __shared__ float sbuf[4];
  const int row = blockIdx.x, b = row >> 10, n = row & 1023, t = threadIdx.x;
  const bf16_t* rp = qkv + (size_t)row * 3072;
  bh4 q4 = *(const bh4*)(rp + t * 4);
  bh4 k4 = *(const bh4*)(rp + 1024 + t * 4);
  bh4 v4 = *(const bh4*)(rp + 2048 + t * 4);
  float4 q = {(float)q4[0], (float)q4[1], (float)q4[2], (float)q4[3]};
  float4 k = {(float)k4[0], (float)k4[1], (float)k4[2], (float)k4[3]};
  float4 v = {(float)v4[0], (float)v4[1], (float)v4[2], (float)v4[3]};
  float sq = q.x*q.x + q.y*q.y + q.z*q.z + q.w*q.w;
  float sk = k.x*k.x + k.y*k.y + k.z*k.z + k.w*k.w;
  float sv = v.x*v.x + v.y*v.y + v.z*v.z + v.w*v.w;
  float tq = block_sum(sq, sbuf);
  float tk = block_sum(sk, sbuf);
  float tv = block_sum(sv, sbuf);
  float rq = rsqrtf(tq * (1.f/1024.f) + 1e-4f);
  float rk = rsqrtf(tk * (1.f/1024.f) + 1e-4f);
  float rv = rsqrtf(tv * (1.f/1024.f) + 1e-4f);
  float hq = sq, hk = sk;   // per-head sums: 16 consecutive threads = one head (within a wave)
#pragma unroll
  for (int m = 1; m < 16; m <<= 1) { hq += __shfl_xor(hq, m, 64); hk += __shfl_xor(hk, m, 64); }
  float qs = rq * rsqrtf(rq*rq*hq + 1e-6f);
  float ks = rk * rsqrtf(rk*rk*hk + 1e-6f);
  int h = t >> 4, d = (t & 15) * 4;
  size_t base = ((size_t)(b * 16 + h) * 1024 + n) * 64 + d;
  bh4 oq, okk, ov;
  oq[0]=(bf16_t)(q.x*qs); oq[1]=(bf16_t)(q.y*qs); oq[2]=(bf16_t)(q.z*qs); oq[3]=(bf16_t)(q.w*qs);
  okk[0]=(bf16_t)(k.x*ks); okk[1]=(bf16_t)(k.y*ks); okk[2]=(bf16_t)(k.z*ks); okk[3]=(bf16_t)(k.w*ks);
  ov[0]=(bf16_t)(v.x*rv); ov[1]=(bf16_t)(v.y*rv); ov[2]=(bf16_t)(v.z*rv); ov[3]=(bf16_t)(v.w*rv);
  *(bh4*)(qo + base) = oq;
  *(bh4*)(ko + base) = okk;
  *(bh4*)(vo + base) = ov;
}

// ---------- one-shot V transpose: vt[bh][d][n] = vh[bh][n][d] ----------
// phase1: coalesced bh8 loads -> b128 LDS writes (padded stride 72).
// phase2: lane=d scalar reads (bank = 4j + d/2 -> 2-way = free), bh8 stores.
__global__ void k_vtrans(const bf16_t* __restrict__ vh, bf16_t* __restrict__ vt) {
  __shared__ bf16_t tile[64][72];
  const int n0 = blockIdx.x * 64, bh = blockIdx.y;
  const int t = threadIdx.x;
  const bf16_t* src = vh + ((size_t)bh * 1024 + n0) * 64;
#pragma unroll
  for (int i = t; i < 512; i += 256) {
    int r = i >> 3, p = (i & 7) * 8;
    *(bh8*)&tile[r][p] = *(const bh8*)(src + r * 64 + p);
  }
  __syncthreads();
  bf16_t* dst = vt + (size_t)bh * 64 * 1024 + n0;
#pragma unroll
  for (int i = t; i < 512; i += 256) {
    int d = i & 63, nch = (i >> 6) * 8;
    bh8 o;
#pragma unroll
    for (int j = 0; j < 8; j++) o[j] = tile[nch + j][d];
    *(bh8*)(dst + (size_t)d * 1024 + nch) = o;
  }
}

// ---------- attention, Q-tile 64, V pre-transposed (no in-kernel transpose) ----------
// scores bounded in [-1/8,1/8] -> no max-subtraction needed
__global__ __launch_bounds__(256) void k_attn(const bf16_t* __restrict__ Q,
                                              const bf16_t* __restrict__ K,
                                              const bf16_t* __restrict__ Vt_g,
                                              bf16_t* __restrict__ O) {
  __shared__ bf16_t Qs[64][72];
  __shared__ bf16_t Ks[64][72];
  __shared__ bf16_t Vt[64][72];   // Vt[dh][kv]
  __shared__ bf16_t Ps[64][72];
  const int qt = blockIdx.x, bh = blockIdx.y;
  const int b = bh >> 4, h = bh & 15;
  const int t = threadIdx.x, lane = t & 63, wid = t >> 6;
  const int l15 = lane & 15, quad = lane >> 4;
  const int strip = wid * 16;
  const bf16_t* Qg = Q + ((size_t)bh * 1024 + qt * 64) * 64;
  const bf16_t* Kg = K + (size_t)bh * 1024 * 64;
  const bf16_t* Vg = Vt_g + (size_t)bh * 64 * 1024;   // [dh][n]
  for (int i = t; i < 512; i += 256) {
    int r = i >> 3, p = (i & 7) * 8;
    *(bh8*)&Qs[r][p] = *(const bh8*)(Qg + r * 64 + p);
  }
  f32x4 o[4] = {};
  float rs[4] = {};
  __syncthreads();
  for (int kv0 = 0; kv0 < 1024; kv0 += 64) {
    for (int i = t; i < 512; i += 256) {
      int r = i >> 3, p = (i & 7) * 8;
      *(bh8*)&Ks[r][p] = *(const bh8*)(Kg + (size_t)(kv0 + r) * 64 + p);
      *(bh8*)&Vt[r][p] = *(const bh8*)(Vg + (size_t)r * 1024 + kv0 + p);
    }
    __syncthreads();
    // S = Q Kt for this wave's 16-row strip
    f32x4 s[4] = {};
#pragma unroll
    for (int kc = 0; kc < 2; kc++) {
      bh8 aq = *(const bh8*)&Qs[strip + l15][kc*32 + quad*8];
      bh8 bk[4];
#pragma unroll
      for (int j = 0; j < 4; j++) bk[j] = *(const bh8*)&Ks[j*16 + l15][kc*32 + quad*8];
#pragma unroll
      for (int j = 0; j < 4; j++)
        s[j] = __builtin_amdgcn_mfma_f32_16x16x32_bf16(aq, bk[j], s[j], 0, 0, 0);
    }
    // P = exp(S/8); accumulate per-lane rowsums; C-layout -> LDS -> A-layout
#pragma unroll
    for (int j = 0; j < 4; j++)
#pragma unroll
      for (int r = 0; r < 4; r++) {
        float p = __expf(s[j][r] * 0.125f);
        bf16_t pb = (bf16_t)p;
        rs[r] += (float)pb;   // keep rs consistent with bf16 P fed to PV
        Ps[strip + quad*4 + r][j*16 + l15] = pb;
      }
    // O += P @ V  (wave reads only its own Ps strip -> no extra barrier needed)
#pragma unroll
    for (int kc = 0; kc < 2; kc++) {
      bh8 ap = *(const bh8*)&Ps[strip + l15][kc*32 + quad*8];
      bh8 bv[4];
#pragma unroll
      for (int j = 0; j < 4; j++) bv[j] = *(const bh8*)&Vt[j*16 + l15][kc*32 + quad*8];
#pragma unroll
      for (int j = 0; j < 4; j++)
        o[j] = __builtin_amdgcn_mfma_f32_16x16x32_bf16(ap, bv[j], o[j], 0, 0, 0);
    }
    __syncthreads();
  }
  // finalize rowsums: sum across the 16 column-lanes of each quad; O rows match rs rows
#pragma unroll
  for (int r = 0; r < 4; r++) {
    float v = rs[r];
    v += __shfl_xor(v, 1, 64); v += __shfl_xor(v, 2, 64);
    v += __shfl_xor(v, 4, 64); v += __shfl_xor(v, 8, 64);
    float inv = 1.f / v;
    int n = qt * 64 + strip + quad*4 + r;
#pragma unroll
    for (int j = 0; j < 4; j++)
      O[((size_t)b * 1024 + n) * 1024 + h*64 + j*16 + l15] = (bf16_t)(o[j][r] * inv);
  }
}

// ---------- x1 = mp_add(x, pixel_norm(y0+y1)*exp(ag)) [bf16 out]; xc2 = bf16(pixel_norm(x1)*(1+g)+s) ----------
__global__ void k_amerge(const bf16_t* __restrict__ y, const float* __restrict__ x,
                         const float* __restrict__ gs, const float* __restrict__ again,
                         bf16_t* __restrict__ x1, bf16_t* __restrict__ xc2) {
  __shared__ float sbuf[4];
  int row = blockIdx.x, b = row >> 10, t = threadIdx.x;
  const size_t PS = (size_t)4096 * 1024;   // split-K partial stride (elements)
  bh4 a0 = *(const bh4*)(y + (size_t)row * 1024 + t * 4);
  bh4 a1 = *(const bh4*)(y + PS + (size_t)row * 1024 + t * 4);
  float4 yv;
  yv.x = (float)a0[0] + (float)a1[0]; yv.y = (float)a0[1] + (float)a1[1];
  yv.z = (float)a0[2] + (float)a1[2]; yv.w = (float)a0[3] + (float)a1[3];
  float4 xv = ((const float4*)(x + (size_t)row * 1024))[t];
  float ss = yv.x*yv.x + yv.y*yv.y + yv.z*yv.z + yv.w*yv.w;
  float tot = block_sum(ss, sbuf);
  float r = rsqrtf(tot * (1.f/1024.f) + 1e-4f);
  float ag = __expf(again[0]);
  const float C1 = 0.7f / 0.76157731059f, C2 = 0.3f / 0.76157731059f; // /sqrt(0.58)
  float4 xo;
  xo.x = C1 * xv.x + C2 * (yv.x * r * ag);
  xo.y = C1 * xv.y + C2 * (yv.y * r * ag);
  xo.z = C1 * xv.z + C2 * (yv.z * r * ag);
  xo.w = C1 * xv.w + C2 * (yv.w * r * ag);
  bh4 x1o;
  x1o[0] = (bf16_t)xo.x; x1o[1] = (bf16_t)xo.y; x1o[2] = (bf16_t)xo.z; x1o[3] = (bf16_t)xo.w;
  *(bh4*)(x1 + (size_t)row * 1024 + t * 4) = x1o;
  float ss1 = xo.x*xo.x + xo.y*xo.y + xo.z*xo.z + xo.w*xo.w;
  float tot1 = block_sum(ss1, sbuf);
  float r1 = rsqrtf(tot1 * (1.f/1024.f) + 1e-4f);
  float4 g  = ((const float4*)(gs + b * 2048))[t];
  float4 sh = ((const float4*)(gs + b * 2048 + 1024))[t];
  bh4 o;
  o[0] = (bf16_t)(xo.x * r1 * (1.f + g.x) + sh.x);
  o[1] = (bf16_t)(xo.y * r1 * (1.f + g.y) + sh.y);
  o[2] = (bf16_t)(xo.z * r1 * (1.f + g.z) + sh.z);
  o[3] = (bf16_t)(xo.w * r1 * (1.f + g.w) + sh.w);
  *(bh4*)(xc2 + (size_t)row * 1024 + t * 4) = o;
}

// ---------- h = bf16(mp_silu(pixel_norm(hf))) over 4096-wide rows, bf16 in ----------
__global__ void k_mlpnorm(const bf16_t* __restrict__ hf, bf16_t* __restrict__ hb) {
  __shared__ float sbuf[4];
  int row = blockIdx.x, t = threadIdx.x;
  const bf16_t* rp = hf + (size_t)row * 4096;
  float4 v[4]; float ss = 0.f;
#pragma unroll
  for (int i = 0; i < 4; i++) {
    bh4 bv = *(const bh4*)(rp + (t + 256 * i) * 4);
    v[i].x = (float)bv[0]; v[i].y = (float)bv[1]; v[i].z = (float)bv[2]; v[i].w = (float)bv[3];
    ss += v[i].x*v[i].x + v[i].y*v[i].y + v[i].z*v[i].z + v[i].w*v[i].w;
  }
  float tot = block_sum(ss, sbuf);
  float r = rsqrtf(tot * (1.f/4096.f) + 1e-4f);
#pragma unroll
  for (int i = 0; i < 4; i++) {
    float a[4] = {v[i].x, v[i].y, v[i].z, v[i].w};
    bh4 o;
#pragma unroll
    for (int j = 0; j < 4; j++) {
      float u = a[j] * r;
      float sig = 1.f / (1.f + __expf(-u));
      o[j] = (bf16_t)(u * sig * (1.f / 0.596f));
    }
    *(bh4*)(hb + (size_t)row * 4096 + (t + 256 * i) * 4) = o;
  }
}

// ---------- out = mp_add(x1, pixel_norm(y0+y1)*exp(mg)) ----------
__global__ void k_fmerge(const bf16_t* __restrict__ y, const bf16_t* __restrict__ x1,
                         const float* __restrict__ mgain, float* __restrict__ out) {
  __shared__ float sbuf[4];
  int row = blockIdx.x, t = threadIdx.x;
  const size_t PS = (size_t)4096 * 1024;
  float4 yv = {0.f, 0.f, 0.f, 0.f};
#pragma unroll
  for (int p = 0; p < 2; p++) {
    bh4 yp = *(const bh4*)(y + p * PS + (size_t)row * 1024 + t * 4);
    yv.x += (float)yp[0]; yv.y += (float)yp[1]; yv.z += (float)yp[2]; yv.w += (float)yp[3];
  }
  bh4 xb = *(const bh4*)(x1 + (size_t)row * 1024 + t * 4);
  float4 xv = {(float)xb[0], (float)xb[1], (float)xb[2], (float)xb[3]};
  float ss = yv.x*yv.x + yv.y*yv.y + yv.z*yv.z + yv.w*yv.w;
  float tot = block_sum(ss, sbuf);
  float r = rsqrtf(tot * (1.f/1024.f) + 1e-4f);
  float mg = __expf(mgain[0]);
  const float C1 = 0.7f / 0.76157731059f, C2 = 0.3f / 0.76157731059f;
  float4 o;
  o.x = C1 * xv.x + C2 * (yv.x * r * mg);
  o.y = C1 * xv.y + C2 * (yv.y * r * mg);
  o.z = C1 * xv.z + C2 * (yv.z * r * mg);
  o.w = C1 * xv.w + C2 * (yv.w * r * mg);
  ((float4*)(out + (size_t)row * 1024))[t] = o;
}

// ---------- launch ----------
extern "C" void kernel_launch(void* const* d_in, const int* in_sizes, int n_in,
                              void* d_out, int out_size, void* d_ws, size_t ws_size,
                              hipStream_t stream) {
  const float* x      = (const float*)d_in[0];
  const float* c      = (const float*)d_in[1];
  const float* w_cond = (const float*)d_in[2];
  const float* w_qkv  = (const float*)d_in[3];
  const float* w_out  = (const float*)d_in[4];
  const float* w_mlp1 = (const float*)d_in[5];
  const float* w_mlp2 = (const float*)d_in[6];
  const float* again  = (const float*)d_in[7];
  const float* mgain  = (const float*)d_in[8];
  float* out = (float*)d_out;
  char* ws = (char*)d_ws;

  // ws layout (bytes)
  bf16_t* wt_cond = (bf16_t*)(ws + 0);                    //  4 MB [2048,1024]
  bf16_t* wt_qkv  = (bf16_t*)(ws + 4194304);              //  6 MB [3072,1024]
  bf16_t* wt_out  = (bf16_t*)(ws + 10485760);             //  2 MB [1024,1024]
  bf16_t* wt_mlp1 = (bf16_t*)(ws + 12582912);             //  8 MB [4096,1024]
  bf16_t* wt_mlp2 = (bf16_t*)(ws + 20971520);             //  8 MB [1024,4096]
  float*  sn      = (float*)(ws + 29360128);              //  32 KB (5 scale arrays, packed)
  float*  gs      = (float*)(ws + 29392896);              //  32 KB [4,2048]
  bf16_t* xc      = (bf16_t*)(ws + 29425664);             //  8 MB (xc, later xc2)
  bf16_t* qh      = (bf16_t*)(ws + 37814272);             //  8 MB
  bf16_t* kh      = (bf16_t*)(ws + 46202880);             //  8 MB
  bf16_t* vh      = (bf16_t*)(ws + 54591488);             //  8 MB
  bf16_t* xattn   = (bf16_t*)(ws + 62980096);             //  8 MB
  bf16_t* hb      = (bf16_t*)(ws + 37814272);             // 32 MB = qh..xattn reused after consumed
  bf16_t* x1      = (bf16_t*)(ws + 71368704);             //  8 MB (bf16 residual)
  bf16_t* vt      = (bf16_t*)(ws + 79757312);             //  8 MB (V^T [bh][dh][n])
  bf16_t* buf_b   = (bf16_t*)(ws + 88145920);             // 32 MB bf16: qkv / y2(x2) / h / y4(x2)

  // weight prep (re-done every call: ws is re-poisoned by harness)
  k_wnorm_all<<<8192, 256, 0, stream>>>(w_cond, w_qkv, w_out, w_mlp1, w_mlp2, sn);
  k_wtrans_all<<<3584, 256, 0, stream>>>(w_cond, w_qkv, w_out, w_mlp1, w_mlp2, sn,
                                         wt_cond, wt_qkv, wt_out, wt_mlp1, wt_mlp2);

  // conditioning
  k_cond<<<512, 256, 0, stream>>>(c, wt_cond, gs);
  // attention branch
  k_xcond<<<4096, 256, 0, stream>>>(x, gs, xc);
  k_gemm<<<dim3(24, 32, 1), 256, 0, stream>>>(xc, wt_qkv, buf_b, 4096, 3072, 1024, 1024);
  k_qkvnorm<<<4096, 256, 0, stream>>>(buf_b, qh, kh, vh);
  k_vtrans<<<dim3(16, 64), 256, 0, stream>>>(vh, vt);
  k_attn<<<dim3(16, 64), 256, 0, stream>>>(qh, kh, vt, xattn);
  k_gemm<<<dim3(8, 32, 2), 256, 0, stream>>>(xattn, wt_out, buf_b, 4096, 1024, 1024, 512);
  k_amerge<<<4096, 256, 0, stream>>>(buf_b, x, gs, again, x1, xc);
  // MLP branch
  k_gemm<<<dim3(32, 32, 1), 256, 0, stream>>>(xc, wt_mlp1, buf_b, 4096, 4096, 1024, 1024);
  k_mlpnorm<<<4096, 256, 0, stream>>>(buf_b, hb);
  k_gemm<<<dim3(8, 32, 2), 256, 0, stream>>>(hb, wt_mlp2, buf_b, 4096, 1024, 4096, 2048);
  k_fmerge<<<4096, 256, 0, stream>>>(buf_b, x1, mgain, out);
  (void)in_sizes; (void)n_in; (void)out_size; (void)ws_size;
}